// Round 1
// baseline (927.060 us; speedup 1.0000x reference)
//
#include <hip/hip_runtime.h>
#include <math.h>

#define BB 8
#define NN 8192
#define DD 128
#define MM 256
#define DVV 128
#define NT 64   // tokens per block

// scale = 1/128^0.25 ; h = 0.5*sum(x_scaled^2) since (x/d^.25)^2 summed = sum(x^2)/sqrt(d)
#define XSCALE 0.29730177875068026f
#define INV_SQRT_M 0.0625f

__device__ __forceinline__ unsigned f2ord(float f) {
    unsigned u = __float_as_uint(f);
    return (u & 0x80000000u) ? ~u : (u | 0x80000000u);
}
__device__ __forceinline__ float ord2f(unsigned u) {
    return (u & 0x80000000u) ? __uint_as_float(u & 0x7fffffffu) : __uint_as_float(~u);
}

__global__ __launch_bounds__(256) void init_kernel(unsigned* __restrict__ kmaxord,
                                                   float* __restrict__ ksum,
                                                   float* __restrict__ kv) {
    int idx = blockIdx.x * 256 + threadIdx.x;
    if (idx < BB) kmaxord[idx] = f2ord(-INFINITY);
    if (idx < BB * MM) ksum[idx] = 0.f;
    if (idx < BB * MM * DVV) kv[idx] = 0.f;
}

// ---------------------------------------------------------------------------
// Pass 1: per-batch max of U_K = (K/d^.25) @ omega
// ---------------------------------------------------------------------------
__global__ __launch_bounds__(256) void kmax_kernel(const float* __restrict__ K,
                                                   const float* __restrict__ omega,
                                                   unsigned* __restrict__ kmaxord) {
    __shared__ __align__(16) float Xs[NT * DD];   // 32 KB
    __shared__ float wred[4];
    const int b = blockIdx.y;
    const int t0 = blockIdx.x * NT;
    const int tid = threadIdx.x;

    const float4* src = (const float4*)(K + ((size_t)b * NN + t0) * DD);
    #pragma unroll
    for (int i = 0; i < 8; ++i) {
        float4 v = src[i * 256 + tid];
        v.x *= XSCALE; v.y *= XSCALE; v.z *= XSCALE; v.w *= XSCALE;
        ((float4*)Xs)[i * 256 + tid] = v;
    }
    __syncthreads();

    const int fm = tid & 63;   // feature group: feats fm*4..fm*4+3
    const int tt = tid >> 6;   // token group: tokens tt*16..tt*16+15
    const float4* om4 = (const float4*)omega;  // [DD][MM/4]

    float acc[4][16];
    #pragma unroll
    for (int j = 0; j < 4; ++j)
        #pragma unroll
        for (int i = 0; i < 16; ++i) acc[j][i] = 0.f;

    for (int dd = 0; dd < DD; ++dd) {
        float4 w = om4[dd * (MM / 4) + fm];
        #pragma unroll
        for (int i = 0; i < 16; ++i) {
            float x = Xs[(tt * 16 + i) * DD + dd];   // wave-broadcast
            acc[0][i] += x * w.x;
            acc[1][i] += x * w.y;
            acc[2][i] += x * w.z;
            acc[3][i] += x * w.w;
        }
    }

    float mx = -INFINITY;
    #pragma unroll
    for (int j = 0; j < 4; ++j)
        #pragma unroll
        for (int i = 0; i < 16; ++i) mx = fmaxf(mx, acc[j][i]);

    #pragma unroll
    for (int off = 32; off; off >>= 1) mx = fmaxf(mx, __shfl_down(mx, off, 64));
    if ((tid & 63) == 0) wred[tid >> 6] = mx;
    __syncthreads();
    if (tid == 0) {
        float m2 = fmaxf(fmaxf(wred[0], wred[1]), fmaxf(wred[2], wred[3]));
        atomicMax(kmaxord + b, f2ord(m2));
    }
}

// ---------------------------------------------------------------------------
// Pass 2: Kp = (exp(U_K - h - kmax)+eps)/sqrt(M)*mask ; Ksum += ; KV += Kp^T V
// ---------------------------------------------------------------------------
__global__ __launch_bounds__(256) void kv_kernel(const float* __restrict__ K,
                                                 const float* __restrict__ V,
                                                 const float* __restrict__ mask,
                                                 const float* __restrict__ omega,
                                                 const unsigned* __restrict__ kmaxord,
                                                 float* __restrict__ ksum,
                                                 float* __restrict__ kv) {
    // smem: first used as Xs [NT*DD] (32KB), then reused as Kp rows stride 260 (65KB)
    __shared__ __align__(16) float smem[NT * 260];
    __shared__ float hs[NT];
    __shared__ float ms[NT];
    const int b = blockIdx.y;
    const int t0 = blockIdx.x * NT;
    const int tid = threadIdx.x;
    float* Xs = smem;

    {
        const float4* src = (const float4*)(K + ((size_t)b * NN + t0) * DD);
        #pragma unroll
        for (int i = 0; i < 8; ++i) {
            float4 v = src[i * 256 + tid];
            v.x *= XSCALE; v.y *= XSCALE; v.z *= XSCALE; v.w *= XSCALE;
            ((float4*)Xs)[i * 256 + tid] = v;
        }
    }
    __syncthreads();

    if (tid < NT) {  // h + mask (rotated index -> conflict-free)
        float sum = 0.f;
        for (int k = 0; k < DD; ++k) {
            int dd = (k + tid) & (DD - 1);
            float x = Xs[tid * DD + dd];
            sum += x * x;
        }
        hs[tid] = 0.5f * sum;
        ms[tid] = mask[(size_t)b * NN + t0 + tid];
    }

    const int fm = tid & 63;
    const int tt = tid >> 6;
    const float4* om4 = (const float4*)omega;
    float acc[4][16];
    #pragma unroll
    for (int j = 0; j < 4; ++j)
        #pragma unroll
        for (int i = 0; i < 16; ++i) acc[j][i] = 0.f;

    for (int dd = 0; dd < DD; ++dd) {
        float4 w = om4[dd * (MM / 4) + fm];
        #pragma unroll
        for (int i = 0; i < 16; ++i) {
            float x = Xs[(tt * 16 + i) * DD + dd];
            acc[0][i] += x * w.x;
            acc[1][i] += x * w.y;
            acc[2][i] += x * w.z;
            acc[3][i] += x * w.w;
        }
    }
    __syncthreads();   // all Xs reads + hs writes done; smem may be overwritten

    const float kmax = ord2f(kmaxord[b]);
    #pragma unroll
    for (int i = 0; i < 16; ++i) {
        int t = tt * 16 + i;
        float hh = hs[t] + kmax;
        float mm_ = ms[t] * INV_SQRT_M;
        float4 kp;
        kp.x = (expf(acc[0][i] - hh) + 1e-4f) * mm_;
        kp.y = (expf(acc[1][i] - hh) + 1e-4f) * mm_;
        kp.z = (expf(acc[2][i] - hh) + 1e-4f) * mm_;
        kp.w = (expf(acc[3][i] - hh) + 1e-4f) * mm_;
        ((float4*)(smem + t * 260))[fm] = kp;
    }
    __syncthreads();

    // Ksum partial
    {
        float ssum = 0.f;
        for (int t = 0; t < NT; ++t) ssum += smem[t * 260 + tid];
        atomicAdd(&ksum[b * MM + tid], ssum);
    }

    // KV partial: thread owns m0..m0+31 x v0..v0+3
    const int vi = tid & 31;
    const int mi = tid >> 5;
    const int v0 = vi * 4;
    const int m0 = mi * 32;
    float acc2[128];
    #pragma unroll
    for (int k = 0; k < 128; ++k) acc2[k] = 0.f;

    const float4* V4 = (const float4*)(V + ((size_t)b * NN + t0) * DVV);
    for (int t = 0; t < NT; ++t) {
        float4 vv = V4[t * (DVV / 4) + vi];
        const float4* kpr = (const float4*)(smem + t * 260 + m0);
        #pragma unroll
        for (int k4 = 0; k4 < 8; ++k4) {
            float4 kp = kpr[k4];
            float kpc[4] = {kp.x, kp.y, kp.z, kp.w};
            #pragma unroll
            for (int c = 0; c < 4; ++c) {
                acc2[(k4 * 4 + c) * 4 + 0] += kpc[c] * vv.x;
                acc2[(k4 * 4 + c) * 4 + 1] += kpc[c] * vv.y;
                acc2[(k4 * 4 + c) * 4 + 2] += kpc[c] * vv.z;
                acc2[(k4 * 4 + c) * 4 + 3] += kpc[c] * vv.w;
            }
        }
    }
    float* kvb = kv + (size_t)b * MM * DVV;
    #pragma unroll
    for (int k = 0; k < 32; ++k)
        #pragma unroll
        for (int j = 0; j < 4; ++j)
            atomicAdd(&kvb[(m0 + k) * DVV + v0 + j], acc2[k * 4 + j]);
}

// ---------------------------------------------------------------------------
// Pass 3: Qp, norm = Qp.Ksum + eps, Out = (Qp @ KV)/norm
// ---------------------------------------------------------------------------
__global__ __launch_bounds__(256) void out_kernel(const float* __restrict__ Q,
                                                  const float* __restrict__ mask,
                                                  const float* __restrict__ omega,
                                                  const float* __restrict__ ksum,
                                                  const float* __restrict__ kv,
                                                  float* __restrict__ out) {
    __shared__ __align__(16) float smem[NT * 260];  // Xs then Qp rows stride 260
    __shared__ float hs[NT];
    __shared__ float ms[NT];
    __shared__ float norms[NT];
    __shared__ __align__(16) float ksums[MM];
    const int b = blockIdx.y;
    const int t0 = blockIdx.x * NT;
    const int tid = threadIdx.x;
    float* Xs = smem;

    {
        const float4* src = (const float4*)(Q + ((size_t)b * NN + t0) * DD);
        #pragma unroll
        for (int i = 0; i < 8; ++i) {
            float4 v = src[i * 256 + tid];
            v.x *= XSCALE; v.y *= XSCALE; v.z *= XSCALE; v.w *= XSCALE;
            ((float4*)Xs)[i * 256 + tid] = v;
        }
        ksums[tid] = ksum[b * MM + tid];
    }
    __syncthreads();

    if (tid < NT) {
        float sum = 0.f;
        for (int k = 0; k < DD; ++k) {
            int dd = (k + tid) & (DD - 1);
            float x = Xs[tid * DD + dd];
            sum += x * x;
        }
        hs[tid] = 0.5f * sum;
        ms[tid] = mask[(size_t)b * NN + t0 + tid];
    }

    const int fm = tid & 63;
    const int tt = tid >> 6;
    const float4* om4 = (const float4*)omega;
    float acc[4][16];
    #pragma unroll
    for (int j = 0; j < 4; ++j)
        #pragma unroll
        for (int i = 0; i < 16; ++i) acc[j][i] = 0.f;

    for (int dd = 0; dd < DD; ++dd) {
        float4 w = om4[dd * (MM / 4) + fm];
        #pragma unroll
        for (int i = 0; i < 16; ++i) {
            float x = Xs[(tt * 16 + i) * DD + dd];
            acc[0][i] += x * w.x;
            acc[1][i] += x * w.y;
            acc[2][i] += x * w.z;
            acc[3][i] += x * w.w;
        }
    }

    // per-token max over all 256 features: local max then wave butterfly
    float tmax[16];
    #pragma unroll
    for (int i = 0; i < 16; ++i)
        tmax[i] = fmaxf(fmaxf(acc[0][i], acc[1][i]), fmaxf(acc[2][i], acc[3][i]));
    #pragma unroll
    for (int off = 1; off < 64; off <<= 1) {
        #pragma unroll
        for (int i = 0; i < 16; ++i)
            tmax[i] = fmaxf(tmax[i], __shfl_xor(tmax[i], off, 64));
    }

    __syncthreads();  // Xs reads + hs done; smem may be overwritten with Qp

    float4 ks = ((const float4*)ksums)[fm];
    float pnorm[16];
    #pragma unroll
    for (int i = 0; i < 16; ++i) {
        int t = tt * 16 + i;
        float hh = hs[t] + tmax[i];
        float mm_ = ms[t] * INV_SQRT_M;
        float4 qp;
        qp.x = (expf(acc[0][i] - hh) + 1e-4f) * mm_;
        qp.y = (expf(acc[1][i] - hh) + 1e-4f) * mm_;
        qp.z = (expf(acc[2][i] - hh) + 1e-4f) * mm_;
        qp.w = (expf(acc[3][i] - hh) + 1e-4f) * mm_;
        ((float4*)(smem + t * 260))[fm] = qp;
        pnorm[i] = qp.x * ks.x + qp.y * ks.y + qp.z * ks.z + qp.w * ks.w;
    }
    #pragma unroll
    for (int off = 1; off < 64; off <<= 1) {
        #pragma unroll
        for (int i = 0; i < 16; ++i)
            pnorm[i] += __shfl_xor(pnorm[i], off, 64);
    }
    if (fm < 16) norms[tt * 16 + fm] = pnorm[fm] + 1e-8f;
    __syncthreads();

    // Out GEMM: thread owns tokens ti*8..+7, cols v0..v0+3
    const int vi = tid & 31;
    const int ti = tid >> 5;
    const int v0 = vi * 4;
    float acc3[32];
    #pragma unroll
    for (int k = 0; k < 32; ++k) acc3[k] = 0.f;

    const float4* kv4 = (const float4*)(kv + (size_t)b * MM * DVV);
    for (int m4 = 0; m4 < MM / 4; ++m4) {
        float4 kr0 = kv4[(m4 * 4 + 0) * (DVV / 4) + vi];
        float4 kr1 = kv4[(m4 * 4 + 1) * (DVV / 4) + vi];
        float4 kr2 = kv4[(m4 * 4 + 2) * (DVV / 4) + vi];
        float4 kr3 = kv4[(m4 * 4 + 3) * (DVV / 4) + vi];
        #pragma unroll
        for (int it = 0; it < 8; ++it) {
            int t = ti * 8 + it;
            float4 qp = ((const float4*)(smem + t * 260))[m4];
            acc3[it * 4 + 0] += qp.x * kr0.x + qp.y * kr1.x + qp.z * kr2.x + qp.w * kr3.x;
            acc3[it * 4 + 1] += qp.x * kr0.y + qp.y * kr1.y + qp.z * kr2.y + qp.w * kr3.y;
            acc3[it * 4 + 2] += qp.x * kr0.z + qp.y * kr1.z + qp.z * kr2.z + qp.w * kr3.z;
            acc3[it * 4 + 3] += qp.x * kr0.w + qp.y * kr1.w + qp.z * kr2.w + qp.w * kr3.w;
        }
    }

    float* outb = out + ((size_t)b * NN + t0) * DVV;
    #pragma unroll
    for (int it = 0; it < 8; ++it) {
        int t = ti * 8 + it;
        float inv = 1.f / norms[t];
        float4 o;
        o.x = acc3[it * 4 + 0] * inv;
        o.y = acc3[it * 4 + 1] * inv;
        o.z = acc3[it * 4 + 2] * inv;
        o.w = acc3[it * 4 + 3] * inv;
        ((float4*)(outb + t * DVV))[vi] = o;
    }
}

extern "C" void kernel_launch(void* const* d_in, const int* in_sizes, int n_in,
                              void* d_out, int out_size, void* d_ws, size_t ws_size,
                              hipStream_t stream) {
    const float* Q     = (const float*)d_in[0];
    const float* K     = (const float*)d_in[1];
    const float* V     = (const float*)d_in[2];
    const float* mask  = (const float*)d_in[3];
    const float* omega = (const float*)d_in[4];
    float* out = (float*)d_out;

    unsigned* kmaxord = (unsigned*)d_ws;                       // 8 uints
    float* ksum = (float*)((char*)d_ws + 1024);                // 8*256 floats
    float* kv   = (float*)((char*)d_ws + 16384);               // 8*256*128 floats (1MB)

    dim3 blk(256);
    init_kernel<<<dim3((BB * MM * DVV) / 256), blk, 0, stream>>>(kmaxord, ksum, kv);
    kmax_kernel<<<dim3(NN / NT, BB), blk, 0, stream>>>(K, omega, kmaxord);
    kv_kernel<<<dim3(NN / NT, BB), blk, 0, stream>>>(K, V, mask, omega, kmaxord, ksum, kv);
    out_kernel<<<dim3(NN / NT, BB), blk, 0, stream>>>(Q, mask, omega, ksum, kv, out);
}

// Round 2
// 532.848 us; speedup vs baseline: 1.7398x; 1.7398x over previous
//
#include <hip/hip_runtime.h>
#include <math.h>

#define BB 8
#define NN 8192
#define DD 128
#define MM 256
#define DVV 128
#define NT 64   // tokens per chunk

// scale = 1/128^0.25 ; h = 0.5*sum(x_scaled^2)
#define XSCALE 0.29730177875068026f
#define INV_SQRT_M 0.0625f

__device__ __forceinline__ unsigned f2ord(float f) {
    unsigned u = __float_as_uint(f);
    return (u & 0x80000000u) ? ~u : (u | 0x80000000u);
}
__device__ __forceinline__ float ord2f(unsigned u) {
    return (u & 0x80000000u) ? __uint_as_float(u & 0x7fffffffu) : __uint_as_float(~u);
}

__global__ __launch_bounds__(256) void init_kernel(unsigned* __restrict__ kmaxord) {
    if (threadIdx.x < BB) kmaxord[threadIdx.x] = f2ord(-INFINITY);
}

// ---------------------------------------------------------------------------
// Pass 1: per-batch max of U_K = (K/d^.25) @ omega
// ---------------------------------------------------------------------------
__global__ __launch_bounds__(256) void kmax_kernel(const float* __restrict__ K,
                                                   const float* __restrict__ omega,
                                                   unsigned* __restrict__ kmaxord) {
    __shared__ __align__(16) float Xs[NT * DD];   // 32 KB
    __shared__ float wred[4];
    const int b = blockIdx.y;
    const int t0 = blockIdx.x * NT;
    const int tid = threadIdx.x;

    {
        const float4* src = (const float4*)(K + ((size_t)b * NN + t0) * DD);
        float4* dst = (float4*)Xs;
        #pragma unroll
        for (int i = 0; i < 8; ++i) {
            float4 v = src[i * 256 + tid];
            v.x *= XSCALE; v.y *= XSCALE; v.z *= XSCALE; v.w *= XSCALE;
            dst[i * 256 + tid] = v;
        }
    }
    __syncthreads();

    const int fm = tid & 63;   // feature float4 index
    const int tt = tid >> 6;   // token group
    const float4* om4 = (const float4*)omega;  // [DD][MM/4]
    const float4* Xs4 = (const float4*)Xs;

    float acc[4][16];
    #pragma unroll
    for (int j = 0; j < 4; ++j)
        #pragma unroll
        for (int i = 0; i < 16; ++i) acc[j][i] = 0.f;

    for (int dd4 = 0; dd4 < DD / 4; ++dd4) {
        float4 w0 = om4[(dd4 * 4 + 0) * (MM / 4) + fm];
        float4 w1 = om4[(dd4 * 4 + 1) * (MM / 4) + fm];
        float4 w2 = om4[(dd4 * 4 + 2) * (MM / 4) + fm];
        float4 w3 = om4[(dd4 * 4 + 3) * (MM / 4) + fm];
        #pragma unroll
        for (int i = 0; i < 16; ++i) {
            float4 x = Xs4[(tt * 16 + i) * (DD / 4) + dd4];  // wave-broadcast
            acc[0][i] += x.x * w0.x + x.y * w1.x + x.z * w2.x + x.w * w3.x;
            acc[1][i] += x.x * w0.y + x.y * w1.y + x.z * w2.y + x.w * w3.y;
            acc[2][i] += x.x * w0.z + x.y * w1.z + x.z * w2.z + x.w * w3.z;
            acc[3][i] += x.x * w0.w + x.y * w1.w + x.z * w2.w + x.w * w3.w;
        }
    }

    float mx = -INFINITY;
    #pragma unroll
    for (int j = 0; j < 4; ++j)
        #pragma unroll
        for (int i = 0; i < 16; ++i) mx = fmaxf(mx, acc[j][i]);

    #pragma unroll
    for (int off = 32; off; off >>= 1) mx = fmaxf(mx, __shfl_down(mx, off, 64));
    if ((tid & 63) == 0) wred[tid >> 6] = mx;
    __syncthreads();
    if (tid == 0) {
        float m2 = fmaxf(fmaxf(wred[0], wred[1]), fmaxf(wred[2], wred[3]));
        atomicMax(kmaxord + b, f2ord(m2));
    }
}

// ---------------------------------------------------------------------------
// Pass 2: Kp = (exp(U_K - h - kmax)+eps)/sqrt(M)*mask ; partial Ksum, KV
// Grid (P, BB). Block p handles tokens [p*NN/P, (p+1)*NN/P) in chunks of NT,
// accumulating its KV partial in registers, then writes its OWN ws slot.
// ---------------------------------------------------------------------------
__global__ __launch_bounds__(256, 2) void kv_kernel(const float* __restrict__ K,
                                                    const float* __restrict__ V,
                                                    const float* __restrict__ mask,
                                                    const float* __restrict__ omega,
                                                    const unsigned* __restrict__ kmaxord,
                                                    float* __restrict__ pkv,
                                                    float* __restrict__ pks,
                                                    int P) {
    __shared__ __align__(16) float smem[NT * 260];  // Xs (64x128) then Kp rows stride 260
    __shared__ float hs[NT];
    __shared__ float ms[NT];
    const int b = blockIdx.y;
    const int p = blockIdx.x;
    const int tid = threadIdx.x;
    const int chunks = (NN / NT) / P;

    const float kmax = ord2f(kmaxord[b]);
    const int fm = tid & 63;
    const int tt = tid >> 6;
    const int vi = tid & 31;
    const int mi = tid >> 5;
    const int m0 = mi * 32;

    float acc2[128];
    #pragma unroll
    for (int k = 0; k < 128; ++k) acc2[k] = 0.f;
    float ksum_acc = 0.f;

    const float4* om4 = (const float4*)omega;

    for (int c = 0; c < chunks; ++c) {
        const int t0 = (p * chunks + c) * NT;
        __syncthreads();  // previous iteration's smem consumers done
        {
            const float4* src = (const float4*)(K + ((size_t)b * NN + t0) * DD);
            float4* dst = (float4*)smem;
            #pragma unroll
            for (int i = 0; i < 8; ++i) {
                float4 v = src[i * 256 + tid];
                v.x *= XSCALE; v.y *= XSCALE; v.z *= XSCALE; v.w *= XSCALE;
                dst[i * 256 + tid] = v;
            }
        }
        __syncthreads();

        if (tid < NT) {  // h + mask (rotated float4 reads)
            float sum = 0.f;
            const float4* xr = (const float4*)(smem + tid * DD);
            for (int j = 0; j < 32; ++j) {
                float4 v = xr[(j + tid) & 31];
                sum += v.x * v.x + v.y * v.y + v.z * v.z + v.w * v.w;
            }
            hs[tid] = 0.5f * sum;
            ms[tid] = mask[(size_t)b * NN + t0 + tid];
        }

        float acc[4][16];
        #pragma unroll
        for (int j = 0; j < 4; ++j)
            #pragma unroll
            for (int i = 0; i < 16; ++i) acc[j][i] = 0.f;

        const float4* Xs4 = (const float4*)smem;
        for (int dd4 = 0; dd4 < DD / 4; ++dd4) {
            float4 w0 = om4[(dd4 * 4 + 0) * (MM / 4) + fm];
            float4 w1 = om4[(dd4 * 4 + 1) * (MM / 4) + fm];
            float4 w2 = om4[(dd4 * 4 + 2) * (MM / 4) + fm];
            float4 w3 = om4[(dd4 * 4 + 3) * (MM / 4) + fm];
            #pragma unroll
            for (int i = 0; i < 16; ++i) {
                float4 x = Xs4[(tt * 16 + i) * (DD / 4) + dd4];
                acc[0][i] += x.x * w0.x + x.y * w1.x + x.z * w2.x + x.w * w3.x;
                acc[1][i] += x.x * w0.y + x.y * w1.y + x.z * w2.y + x.w * w3.y;
                acc[2][i] += x.x * w0.z + x.y * w1.z + x.z * w2.z + x.w * w3.z;
                acc[3][i] += x.x * w0.w + x.y * w1.w + x.z * w2.w + x.w * w3.w;
            }
        }
        __syncthreads();  // Xs reads + hs writes done; smem may be overwritten

        #pragma unroll
        for (int i = 0; i < 16; ++i) {
            int t = tt * 16 + i;
            float hh = hs[t] + kmax;
            float mm_ = ms[t] * INV_SQRT_M;
            float4 kp;
            kp.x = (__expf(acc[0][i] - hh) + 1e-4f) * mm_;
            kp.y = (__expf(acc[1][i] - hh) + 1e-4f) * mm_;
            kp.z = (__expf(acc[2][i] - hh) + 1e-4f) * mm_;
            kp.w = (__expf(acc[3][i] - hh) + 1e-4f) * mm_;
            ((float4*)(smem + t * 260))[fm] = kp;
        }
        __syncthreads();

        {   // Ksum partial for feature column tid
            float s = 0.f;
            for (int t = 0; t < NT; ++t) s += smem[t * 260 + tid];
            ksum_acc += s;
        }

        // KV partial: thread owns feats m0..m0+31 x cols vi*4..vi*4+3
        const float4* V4 = (const float4*)(V + ((size_t)b * NN + t0) * DVV);
        for (int t = 0; t < NT; ++t) {
            float4 vv = V4[t * (DVV / 4) + vi];
            const float4* kpr = (const float4*)(smem + t * 260 + m0);
            #pragma unroll
            for (int k4 = 0; k4 < 8; ++k4) {
                float4 kp = kpr[k4];
                float kpc[4] = {kp.x, kp.y, kp.z, kp.w};
                #pragma unroll
                for (int cc = 0; cc < 4; ++cc) {
                    acc2[(k4 * 4 + cc) * 4 + 0] += kpc[cc] * vv.x;
                    acc2[(k4 * 4 + cc) * 4 + 1] += kpc[cc] * vv.y;
                    acc2[(k4 * 4 + cc) * 4 + 2] += kpc[cc] * vv.z;
                    acc2[(k4 * 4 + cc) * 4 + 3] += kpc[cc] * vv.w;
                }
            }
        }
    }

    // plain coalesced stores to this block's private slot — no atomics
    float* dst = pkv + (size_t)(b * P + p) * (MM * DVV);
    #pragma unroll
    for (int k = 0; k < 32; ++k) {
        float4 o = {acc2[k * 4 + 0], acc2[k * 4 + 1], acc2[k * 4 + 2], acc2[k * 4 + 3]};
        ((float4*)(dst + (m0 + k) * DVV))[vi] = o;
    }
    pks[(size_t)(b * P + p) * MM + tid] = ksum_acc;
}

// ---------------------------------------------------------------------------
// Reduce P partials -> final kv, ksum
// ---------------------------------------------------------------------------
__global__ __launch_bounds__(256) void reduce_kernel(const float* __restrict__ pkv,
                                                     const float* __restrict__ pks,
                                                     float* __restrict__ kv,
                                                     float* __restrict__ ksum,
                                                     int P) {
    const int x = blockIdx.x;       // 0..255
    const int b = x >> 5;
    const int r = (x & 31) * 256 + threadIdx.x;   // float4 idx within batch, 0..8191
    const float4* src = (const float4*)pkv;
    float4 a = {0.f, 0.f, 0.f, 0.f};
    for (int p = 0; p < P; ++p) {
        float4 v = src[(size_t)(b * P + p) * (MM * DVV / 4) + r];
        a.x += v.x; a.y += v.y; a.z += v.z; a.w += v.w;
    }
    ((float4*)kv)[b * (MM * DVV / 4) + r] = a;
    if ((x & 31) == 0) {
        float s = 0.f;
        for (int p = 0; p < P; ++p) s += pks[(size_t)(b * P + p) * MM + threadIdx.x];
        ksum[b * MM + threadIdx.x] = s;
    }
}

// ---------------------------------------------------------------------------
// Pass 3: Qp, norm = Qp.Ksum + eps, Out = (Qp @ KV)/norm
// ---------------------------------------------------------------------------
__global__ __launch_bounds__(256, 2) void out_kernel(const float* __restrict__ Q,
                                                     const float* __restrict__ mask,
                                                     const float* __restrict__ omega,
                                                     const float* __restrict__ ksum,
                                                     const float* __restrict__ kv,
                                                     float* __restrict__ out) {
    __shared__ __align__(16) float smem[NT * 260];  // Xs then Qp rows stride 260
    __shared__ float hs[NT];
    __shared__ float ms[NT];
    __shared__ float norms[NT];
    __shared__ __align__(16) float ksums[MM];
    const int b = blockIdx.y;
    const int t0 = blockIdx.x * NT;
    const int tid = threadIdx.x;

    {
        const float4* src = (const float4*)(Q + ((size_t)b * NN + t0) * DD);
        float4* dst = (float4*)smem;
        #pragma unroll
        for (int i = 0; i < 8; ++i) {
            float4 v = src[i * 256 + tid];
            v.x *= XSCALE; v.y *= XSCALE; v.z *= XSCALE; v.w *= XSCALE;
            dst[i * 256 + tid] = v;
        }
        ksums[tid] = ksum[b * MM + tid];
    }
    __syncthreads();

    if (tid < NT) {
        float sum = 0.f;
        const float4* xr = (const float4*)(smem + tid * DD);
        for (int j = 0; j < 32; ++j) {
            float4 v = xr[(j + tid) & 31];
            sum += v.x * v.x + v.y * v.y + v.z * v.z + v.w * v.w;
        }
        hs[tid] = 0.5f * sum;
        ms[tid] = mask[(size_t)b * NN + t0 + tid];
    }

    const int fm = tid & 63;
    const int tt = tid >> 6;
    const float4* om4 = (const float4*)omega;
    const float4* Xs4 = (const float4*)smem;
    float acc[4][16];
    #pragma unroll
    for (int j = 0; j < 4; ++j)
        #pragma unroll
        for (int i = 0; i < 16; ++i) acc[j][i] = 0.f;

    for (int dd4 = 0; dd4 < DD / 4; ++dd4) {
        float4 w0 = om4[(dd4 * 4 + 0) * (MM / 4) + fm];
        float4 w1 = om4[(dd4 * 4 + 1) * (MM / 4) + fm];
        float4 w2 = om4[(dd4 * 4 + 2) * (MM / 4) + fm];
        float4 w3 = om4[(dd4 * 4 + 3) * (MM / 4) + fm];
        #pragma unroll
        for (int i = 0; i < 16; ++i) {
            float4 x = Xs4[(tt * 16 + i) * (DD / 4) + dd4];
            acc[0][i] += x.x * w0.x + x.y * w1.x + x.z * w2.x + x.w * w3.x;
            acc[1][i] += x.x * w0.y + x.y * w1.y + x.z * w2.y + x.w * w3.y;
            acc[2][i] += x.x * w0.z + x.y * w1.z + x.z * w2.z + x.w * w3.z;
            acc[3][i] += x.x * w0.w + x.y * w1.w + x.z * w2.w + x.w * w3.w;
        }
    }

    // per-token max over all 256 features
    float tmax[16];
    #pragma unroll
    for (int i = 0; i < 16; ++i)
        tmax[i] = fmaxf(fmaxf(acc[0][i], acc[1][i]), fmaxf(acc[2][i], acc[3][i]));
    #pragma unroll
    for (int off = 1; off < 64; off <<= 1) {
        #pragma unroll
        for (int i = 0; i < 16; ++i)
            tmax[i] = fmaxf(tmax[i], __shfl_xor(tmax[i], off, 64));
    }

    __syncthreads();  // Xs reads + hs done; smem may be overwritten with Qp

    float4 ks = ((const float4*)ksums)[fm];
    float pnorm[16];
    #pragma unroll
    for (int i = 0; i < 16; ++i) {
        int t = tt * 16 + i;
        float hh = hs[t] + tmax[i];
        float mm_ = ms[t] * INV_SQRT_M;
        float4 qp;
        qp.x = (__expf(acc[0][i] - hh) + 1e-4f) * mm_;
        qp.y = (__expf(acc[1][i] - hh) + 1e-4f) * mm_;
        qp.z = (__expf(acc[2][i] - hh) + 1e-4f) * mm_;
        qp.w = (__expf(acc[3][i] - hh) + 1e-4f) * mm_;
        ((float4*)(smem + t * 260))[fm] = qp;
        pnorm[i] = qp.x * ks.x + qp.y * ks.y + qp.z * ks.z + qp.w * ks.w;
    }
    #pragma unroll
    for (int off = 1; off < 64; off <<= 1) {
        #pragma unroll
        for (int i = 0; i < 16; ++i)
            pnorm[i] += __shfl_xor(pnorm[i], off, 64);
    }
    if (fm < 16) norms[tt * 16 + fm] = pnorm[fm] + 1e-8f;
    __syncthreads();

    // Out GEMM: thread owns tokens ti*8..+7, cols vi*4..+3
    const int vi = tid & 31;
    const int ti = tid >> 5;
    float acc3[32];
    #pragma unroll
    for (int k = 0; k < 32; ++k) acc3[k] = 0.f;

    const float4* kv4 = (const float4*)(kv + (size_t)b * MM * DVV);
    for (int m4 = 0; m4 < MM / 4; ++m4) {
        float4 kr0 = kv4[(m4 * 4 + 0) * (DVV / 4) + vi];
        float4 kr1 = kv4[(m4 * 4 + 1) * (DVV / 4) + vi];
        float4 kr2 = kv4[(m4 * 4 + 2) * (DVV / 4) + vi];
        float4 kr3 = kv4[(m4 * 4 + 3) * (DVV / 4) + vi];
        #pragma unroll
        for (int it = 0; it < 8; ++it) {
            int t = ti * 8 + it;
            float4 qp = ((const float4*)(smem + t * 260))[m4];
            acc3[it * 4 + 0] += qp.x * kr0.x + qp.y * kr1.x + qp.z * kr2.x + qp.w * kr3.x;
            acc3[it * 4 + 1] += qp.x * kr0.y + qp.y * kr1.y + qp.z * kr2.y + qp.w * kr3.y;
            acc3[it * 4 + 2] += qp.x * kr0.z + qp.y * kr1.z + qp.z * kr2.z + qp.w * kr3.z;
            acc3[it * 4 + 3] += qp.x * kr0.w + qp.y * kr1.w + qp.z * kr2.w + qp.w * kr3.w;
        }
    }

    float* outb = out + ((size_t)b * NN + t0) * DVV;
    #pragma unroll
    for (int it = 0; it < 8; ++it) {
        int t = ti * 8 + it;
        float inv = 1.f / norms[t];
        float4 o;
        o.x = acc3[it * 4 + 0] * inv;
        o.y = acc3[it * 4 + 1] * inv;
        o.z = acc3[it * 4 + 2] * inv;
        o.w = acc3[it * 4 + 3] * inv;
        ((float4*)(outb + t * DVV))[vi] = o;
    }
}

extern "C" void kernel_launch(void* const* d_in, const int* in_sizes, int n_in,
                              void* d_out, int out_size, void* d_ws, size_t ws_size,
                              hipStream_t stream) {
    const float* Q     = (const float*)d_in[0];
    const float* K     = (const float*)d_in[1];
    const float* V     = (const float*)d_in[2];
    const float* mask  = (const float*)d_in[3];
    const float* omega = (const float*)d_in[4];
    float* out = (float*)d_out;

    unsigned* kmaxord = (unsigned*)d_ws;                 // 8 uints
    float* ksum = (float*)((char*)d_ws + 1024);          // 8*256 floats
    float* kv   = (float*)((char*)d_ws + 16384);         // 8*256*128 floats (1 MB)

    // pick split-N factor P (power of 2) by available workspace
    int P = 0;
    for (int cand = 64; cand >= 1; cand >>= 1) {
        size_t need = (size_t)2 * 1024 * 1024
                    + (size_t)cand * 1024 * 1024        // pkv: 8*P*32768 floats
                    + (size_t)cand * 8 * 1024;          // pks: 8*P*256 floats
        if (need <= ws_size) { P = cand; break; }
    }
    float* pkv;
    float* pks;
    if (P == 0) {           // tiny ws fallback: P=1 aliased onto finals
        P = 1;
        pkv = kv;
        pks = ksum;
    } else {
        pkv = (float*)((char*)d_ws + 2 * 1024 * 1024);
        pks = pkv + (size_t)BB * P * MM * DVV;
    }

    dim3 blk(256);
    init_kernel<<<1, blk, 0, stream>>>(kmaxord);
    kmax_kernel<<<dim3(NN / NT, BB), blk, 0, stream>>>(K, omega, kmaxord);
    kv_kernel<<<dim3(P, BB), blk, 0, stream>>>(K, V, mask, omega, kmaxord, pkv, pks, P);
    reduce_kernel<<<dim3(256), blk, 0, stream>>>(pkv, pks, kv, ksum, P);
    out_kernel<<<dim3(NN / NT, BB), blk, 0, stream>>>(Q, mask, omega, ksum, kv, out);
}

// Round 3
// 250.471 us; speedup vs baseline: 3.7013x; 2.1274x over previous
//
#include <hip/hip_runtime.h>
#include <math.h>

#define BB 8
#define NN 8192
#define DD 128
#define MM 256
#define DVV 128
#define PP 32        // split-N partial blocks per batch
#define CHUNK 32     // tokens per chunk

#define XSCALE 0.29730177875068026f
#define INV_SQRT_M 0.0625f

typedef _Float16 f16x8 __attribute__((ext_vector_type(8)));
typedef float f32x16 __attribute__((ext_vector_type(16)));

// LDS fragment slab: 64 lanes x 8 halves, stride 520 (16B-aligned, bank-spread)
#define FR(s, l) ((s) * 520 + (l) * 8)

__device__ __forceinline__ unsigned f2ord(float f) {
    unsigned u = __float_as_uint(f);
    return (u & 0x80000000u) ? ~u : (u | 0x80000000u);
}
__device__ __forceinline__ float ord2f(unsigned u) {
    return (u & 0x80000000u) ? __uint_as_float(u & 0x7fffffffu) : __uint_as_float(~u);
}
__device__ __forceinline__ f32x16 mfma16(f16x8 a, f16x8 b, f32x16 c) {
    return __builtin_amdgcn_mfma_f32_32x32x16_f16(a, b, c, 0, 0, 0);
}
__device__ __forceinline__ int rowf(int r, int q) { return (r & 3) + 8 * (r >> 2) + 4 * q; }

// Stage X (A-operand): src row-major [32][128] fp32 -> scaled hi/lo f16 frags in R1.
// Slabs: comp*8 + ks (ks = k/16). Also h (=0.5*sum xs^2) and mask.
__device__ __forceinline__ void stage_A(const float* __restrict__ src,
                                        _Float16* R1, float* hs, float* msk,
                                        const float* __restrict__ mrow, bool do_h) {
    const int tid = threadIdx.x;
    const int t = tid >> 3, ks = tid & 7;
    const float4* s4 = (const float4*)(src + t * DD + ks * 16);
    float x[16];
    #pragma unroll
    for (int u = 0; u < 4; ++u) {
        float4 v = s4[u];
        x[u*4+0] = v.x * XSCALE; x[u*4+1] = v.y * XSCALE;
        x[u*4+2] = v.z * XSCALE; x[u*4+3] = v.w * XSCALE;
    }
    if (do_h) {
        float p = 0.f;
        #pragma unroll
        for (int u = 0; u < 16; ++u) p += x[u] * x[u];
        p += __shfl_xor(p, 1, 64); p += __shfl_xor(p, 2, 64); p += __shfl_xor(p, 4, 64);
        if (ks == 0) { hs[t] = 0.5f * p; msk[t] = mrow[t]; }
    }
    #pragma unroll
    for (int q = 0; q < 2; ++q) {
        f16x8 h8, l8;
        #pragma unroll
        for (int j = 0; j < 8; ++j) {
            float xv = x[q*8 + j];
            _Float16 h = (_Float16)xv;
            h8[j] = h; l8[j] = (_Float16)(xv - (float)h);
        }
        *(f16x8*)&R1[FR(0*8 + ks, q*32 + t)] = h8;
        *(f16x8*)&R1[FR(1*8 + ks, q*32 + t)] = l8;
    }
}

// Stage V (B-operand): src [32 rows=k][128 cols=n] fp32 -> hi/lo frags in R1.
// Slabs: (comp*4 + vt)*2 + tstep.
__device__ __forceinline__ void stage_BV(const float* __restrict__ src, _Float16* R1) {
    const int tid = threadIdx.x;
    const int t = tid >> 3, c0 = (tid & 7) * 16;
    const int ts = t >> 4, qq = (t >> 3) & 1, j = t & 7;
    const float4* s4 = (const float4*)(src + t * DVV + c0);
    #pragma unroll
    for (int u = 0; u < 4; ++u) {
        float4 v = s4[u];
        float vv[4] = {v.x, v.y, v.z, v.w};
        #pragma unroll
        for (int e = 0; e < 4; ++e) {
            int c = c0 + u*4 + e;
            int vt = c >> 5, iv = c & 31;
            _Float16 h = (_Float16)vv[e];
            R1[FR((0*4 + vt)*2 + ts, qq*32 + iv) + j] = h;
            R1[FR((1*4 + vt)*2 + ts, qq*32 + iv) + j] = (_Float16)(vv[e] - (float)h);
        }
    }
}

// ---------------------------------------------------------------------------
// pack: omega -> B-frag layout hi/lo f16 in ws; init kmaxord
// ---------------------------------------------------------------------------
__global__ __launch_bounds__(256) void pack_kernel(const float* __restrict__ omega,
                                                   _Float16* __restrict__ omh,
                                                   _Float16* __restrict__ oml,
                                                   unsigned* __restrict__ kmaxord) {
    int g = blockIdx.x * 256 + threadIdx.x;    // 0..4095
    if (g < BB) kmaxord[g] = f2ord(-INFINITY);
    int lane = g & 63, ks = (g >> 6) & 7, nt = g >> 9;
    int q = lane >> 5, i = lane & 31;
    f16x8 h8, l8;
    #pragma unroll
    for (int j = 0; j < 8; ++j) {
        float w = omega[(size_t)(ks*16 + q*8 + j) * MM + nt*32 + i];
        _Float16 h = (_Float16)w;
        h8[j] = h; l8[j] = (_Float16)(w - (float)h);
    }
    ((f16x8*)omh)[g] = h8;
    ((f16x8*)oml)[g] = l8;
}

// ---------------------------------------------------------------------------
// kmax: per-batch max of U_K (hi*hi only -- mx error cancels in the ratio)
// ---------------------------------------------------------------------------
__global__ __launch_bounds__(256, 2) void kmax_kernel(const float* __restrict__ K,
                                                      const _Float16* __restrict__ omh,
                                                      unsigned* __restrict__ kmaxord) {
    __shared__ __align__(16) _Float16 R1[16 * 520];
    __shared__ float wred[4];
    const int b = blockIdx.y;
    const int tid = threadIdx.x, w = tid >> 6, lane = tid & 63;

    f16x8 om[2][8];
    #pragma unroll
    for (int n = 0; n < 2; ++n)
        #pragma unroll
        for (int k = 0; k < 8; ++k)
            om[n][k] = ((const f16x8*)omh)[((2*w + n)*8 + k)*64 + lane];

    float mx = -INFINITY;
    for (int c = 0; c < 8; ++c) {
        int t0 = (blockIdx.x * 8 + c) * CHUNK;
        __syncthreads();
        stage_A(K + ((size_t)b*NN + t0) * DD, R1, nullptr, nullptr, nullptr, false);
        __syncthreads();
        f32x16 a0, a1;
        #pragma unroll
        for (int r = 0; r < 16; ++r) { a0[r] = 0.f; a1[r] = 0.f; }
        #pragma unroll
        for (int ks = 0; ks < 8; ++ks) {
            f16x8 ah = *(const f16x8*)&R1[FR(ks, lane)];
            a0 = mfma16(ah, om[0][ks], a0);
            a1 = mfma16(ah, om[1][ks], a1);
        }
        #pragma unroll
        for (int r = 0; r < 16; ++r) mx = fmaxf(mx, fmaxf(a0[r], a1[r]));
    }
    #pragma unroll
    for (int off = 1; off < 64; off <<= 1) mx = fmaxf(mx, __shfl_xor(mx, off, 64));
    if (lane == 0) wred[w] = mx;
    __syncthreads();
    if (tid == 0)
        atomicMax(kmaxord + b,
                  f2ord(fmaxf(fmaxf(wred[0], wred[1]), fmaxf(wred[2], wred[3]))));
}

// ---------------------------------------------------------------------------
// kv: U_K (3-mfma split) -> Kp -> LDS transpose -> KV = Kp^T V (3-mfma split)
// ---------------------------------------------------------------------------
__global__ __launch_bounds__(256) void kv_kernel(const float* __restrict__ K,
                                                 const float* __restrict__ V,
                                                 const float* __restrict__ mask,
                                                 const _Float16* __restrict__ omh,
                                                 const _Float16* __restrict__ oml,
                                                 const unsigned* __restrict__ kmaxord,
                                                 float* __restrict__ pkv,
                                                 float* __restrict__ pks) {
    __shared__ __align__(16) _Float16 R1[16 * 520];
    __shared__ __align__(16) _Float16 R2[32 * 520];
    __shared__ float hs[32], msk[32];
    const int b = blockIdx.y, p = blockIdx.x;
    const int tid = threadIdx.x, w = tid >> 6, lane = tid & 63;
    const int i = tid & 31, q = (tid >> 5) & 1;
    const float kmaxv = ord2f(kmaxord[b]);

    f16x8 omf[2][2][8];   // [comp][n][ks]
    #pragma unroll
    for (int n = 0; n < 2; ++n)
        #pragma unroll
        for (int k = 0; k < 8; ++k) {
            omf[0][n][k] = ((const f16x8*)omh)[((2*w + n)*8 + k)*64 + lane];
            omf[1][n][k] = ((const f16x8*)oml)[((2*w + n)*8 + k)*64 + lane];
        }

    f32x16 kvacc[2][4];
    #pragma unroll
    for (int f = 0; f < 2; ++f)
        #pragma unroll
        for (int vt = 0; vt < 4; ++vt)
            #pragma unroll
            for (int r = 0; r < 16; ++r) kvacc[f][vt][r] = 0.f;
    float ksa[2] = {0.f, 0.f};

    for (int c = 0; c < 8; ++c) {
        int t0 = (p * 8 + c) * CHUNK;
        __syncthreads();
        stage_A(K + ((size_t)b*NN + t0) * DD, R1, hs, msk,
                mask + (size_t)b*NN + t0, true);
        __syncthreads();

        f32x16 a0, a1;
        #pragma unroll
        for (int r = 0; r < 16; ++r) { a0[r] = 0.f; a1[r] = 0.f; }
        #pragma unroll
        for (int ks = 0; ks < 8; ++ks) {
            f16x8 ah = *(const f16x8*)&R1[FR(ks, lane)];
            f16x8 al = *(const f16x8*)&R1[FR(8 + ks, lane)];
            a0 = mfma16(ah, omf[0][0][ks], a0);
            a0 = mfma16(ah, omf[1][0][ks], a0);
            a0 = mfma16(al, omf[0][0][ks], a0);
            a1 = mfma16(ah, omf[0][1][ks], a1);
            a1 = mfma16(ah, omf[1][1][ks], a1);
            a1 = mfma16(al, omf[0][1][ks], a1);
        }
        __syncthreads();   // R1 consumers done -> restage as V; write Kp to R2

        stage_BV(V + ((size_t)b*NN + t0) * DVV, R1);
        #pragma unroll
        for (int r = 0; r < 16; ++r) {
            int tok = rowf(r, q);
            float hh = hs[tok] + kmaxv;
            float mm = msk[tok] * INV_SQRT_M;
            int ts = tok >> 4, qq = (tok >> 3) & 1, j = tok & 7;
            {
                float kp = (__expf(a0[r] - hh) + 1e-4f) * mm;
                ksa[0] += kp;
                _Float16 h = (_Float16)kp;
                R2[FR((2*w + 0)*2 + ts, qq*32 + i) + j] = h;
                R2[FR(16 + (2*w + 0)*2 + ts, qq*32 + i) + j] = (_Float16)(kp - (float)h);
            }
            {
                float kp = (__expf(a1[r] - hh) + 1e-4f) * mm;
                ksa[1] += kp;
                _Float16 h = (_Float16)kp;
                R2[FR((2*w + 1)*2 + ts, qq*32 + i) + j] = h;
                R2[FR(16 + (2*w + 1)*2 + ts, qq*32 + i) + j] = (_Float16)(kp - (float)h);
            }
        }
        __syncthreads();

        #pragma unroll
        for (int f = 0; f < 2; ++f) {
            int ft = 2*w + f;
            f16x8 ah[2], al[2];
            #pragma unroll
            for (int ts = 0; ts < 2; ++ts) {
                ah[ts] = *(const f16x8*)&R2[FR(ft*2 + ts, lane)];
                al[ts] = *(const f16x8*)&R2[FR(16 + ft*2 + ts, lane)];
            }
            #pragma unroll
            for (int vt = 0; vt < 4; ++vt) {
                #pragma unroll
                for (int ts = 0; ts < 2; ++ts) {
                    f16x8 bh = *(const f16x8*)&R1[FR(vt*2 + ts, lane)];
                    f16x8 bl = *(const f16x8*)&R1[FR(8 + vt*2 + ts, lane)];
                    kvacc[f][vt] = mfma16(ah[ts], bh, kvacc[f][vt]);
                    kvacc[f][vt] = mfma16(ah[ts], bl, kvacc[f][vt]);
                    kvacc[f][vt] = mfma16(al[ts], bh, kvacc[f][vt]);
                }
            }
        }
    }

    float* dst = pkv + ((size_t)(b * PP + p) << 15);
    #pragma unroll
    for (int f = 0; f < 2; ++f)
        #pragma unroll
        for (int vt = 0; vt < 4; ++vt)
            #pragma unroll
            for (int r = 0; r < 16; ++r) {
                int feat = (2*w + f)*32 + rowf(r, q);
                dst[feat * DVV + vt*32 + i] = kvacc[f][vt][r];
            }
    #pragma unroll
    for (int n = 0; n < 2; ++n) {
        float s = ksa[n] + __shfl_xor(ksa[n], 32, 64);
        if (q == 0) pks[(size_t)(b * PP + p) * MM + (2*w + n)*32 + i] = s;
    }
}

// ---------------------------------------------------------------------------
// reduce: sum P partials -> ksum fp32 + KV as hi/lo f16 B-frags (global)
// ---------------------------------------------------------------------------
__global__ __launch_bounds__(256) void reduce_kernel(const float* __restrict__ pkv,
                                                     const float* __restrict__ pks,
                                                     float* __restrict__ ksum,
                                                     _Float16* __restrict__ kvph,
                                                     _Float16* __restrict__ kvpl) {
    const int b = blockIdx.y;
    int g = blockIdx.x * 256 + threadIdx.x;     // 0..32767
    float s = 0.f;
    for (int p = 0; p < PP; ++p) s += pkv[((size_t)(b * PP + p) << 15) + g];
    int f = g >> 7, v = g & 127;
    int vt = v >> 5, iv = v & 31, fs = f >> 4, qq = (f >> 3) & 1, j = f & 7;
    size_t idx = (size_t)b * 32768 + (size_t)((vt*16 + fs)*64 + qq*32 + iv)*8 + j;
    _Float16 h = (_Float16)s;
    kvph[idx] = h;
    kvpl[idx] = (_Float16)(s - (float)h);
    if (blockIdx.x == 0) {
        float ss = 0.f;
        for (int p = 0; p < PP; ++p) ss += pks[(size_t)(b * PP + p) * MM + g];
        ksum[b * MM + g] = ss;
    }
}

// ---------------------------------------------------------------------------
// out: U_Q -> per-token max -> Qp frags -> Out = Qp@KV (MFMA), norm via MFMA
// ---------------------------------------------------------------------------
__global__ __launch_bounds__(256) void out_kernel(const float* __restrict__ Q,
                                                  const float* __restrict__ mask,
                                                  const _Float16* __restrict__ omh,
                                                  const _Float16* __restrict__ oml,
                                                  const float* __restrict__ ksum,
                                                  const _Float16* __restrict__ kvph,
                                                  const _Float16* __restrict__ kvpl,
                                                  float* __restrict__ out) {
    __shared__ __align__(16) _Float16 R1[16 * 520];
    __shared__ __align__(16) _Float16 R2[32 * 520];
    __shared__ float hs[32], msk[32], wmax[4][32], norms[32];
    const int b = blockIdx.y;
    const int tid = threadIdx.x, w = tid >> 6, lane = tid & 63;
    const int i = tid & 31, q = (tid >> 5) & 1;

    f16x8 omf[2][2][8];
    #pragma unroll
    for (int n = 0; n < 2; ++n)
        #pragma unroll
        for (int k = 0; k < 8; ++k) {
            omf[0][n][k] = ((const f16x8*)omh)[((2*w + n)*8 + k)*64 + lane];
            omf[1][n][k] = ((const f16x8*)oml)[((2*w + n)*8 + k)*64 + lane];
        }
    f16x8 bfh[16], bfl[16];   // KV B-frags for this wave's vt=w
    #pragma unroll
    for (int fs = 0; fs < 16; ++fs) {
        bfh[fs] = ((const f16x8*)kvph)[(size_t)b * 4096 + (w*16 + fs)*64 + lane];
        bfl[fs] = ((const f16x8*)kvpl)[(size_t)b * 4096 + (w*16 + fs)*64 + lane];
    }
    f16x8 bnh[4], bnl[4];     // Ksum column frags, fsteps w*4..w*4+3
    #pragma unroll
    for (int u = 0; u < 4; ++u) {
        f16x8 hh, ll;
        #pragma unroll
        for (int j = 0; j < 8; ++j) { hh[j] = (_Float16)0.f; ll[j] = (_Float16)0.f; }
        if (i == 0) {
            #pragma unroll
            for (int j = 0; j < 8; ++j) {
                float s = ksum[b * MM + (4*w + u)*16 + q*8 + j];
                _Float16 h = (_Float16)s;
                hh[j] = h; ll[j] = (_Float16)(s - (float)h);
            }
        }
        bnh[u] = hh; bnl[u] = ll;
    }

    for (int c = 0; c < 8; ++c) {
        int t0 = (blockIdx.x * 8 + c) * CHUNK;
        __syncthreads();
        stage_A(Q + ((size_t)b*NN + t0) * DD, R1, hs, msk,
                mask + (size_t)b*NN + t0, true);
        if (tid < 32) norms[tid] = 1e-8f;
        __syncthreads();

        f32x16 a0, a1;
        #pragma unroll
        for (int r = 0; r < 16; ++r) { a0[r] = 0.f; a1[r] = 0.f; }
        #pragma unroll
        for (int ks = 0; ks < 8; ++ks) {
            f16x8 ah = *(const f16x8*)&R1[FR(ks, lane)];
            f16x8 al = *(const f16x8*)&R1[FR(8 + ks, lane)];
            a0 = mfma16(ah, omf[0][0][ks], a0);
            a0 = mfma16(ah, omf[1][0][ks], a0);
            a0 = mfma16(al, omf[0][0][ks], a0);
            a1 = mfma16(ah, omf[0][1][ks], a1);
            a1 = mfma16(ah, omf[1][1][ks], a1);
            a1 = mfma16(al, omf[0][1][ks], a1);
        }
        float tm[16];
        #pragma unroll
        for (int r = 0; r < 16; ++r) tm[r] = fmaxf(a0[r], a1[r]);
        #pragma unroll
        for (int off = 1; off < 32; off <<= 1)
            #pragma unroll
            for (int r = 0; r < 16; ++r) tm[r] = fmaxf(tm[r], __shfl_xor(tm[r], off, 64));
        if (i == 0)
            #pragma unroll
            for (int r = 0; r < 16; ++r) wmax[w][rowf(r, q)] = tm[r];
        __syncthreads();

        #pragma unroll
        for (int r = 0; r < 16; ++r) {
            int tok = rowf(r, q);
            float tmax = fmaxf(fmaxf(wmax[0][tok], wmax[1][tok]),
                               fmaxf(wmax[2][tok], wmax[3][tok]));
            float hh = hs[tok] + tmax;
            float mm = msk[tok] * INV_SQRT_M;
            #pragma unroll
            for (int n = 0; n < 2; ++n) {
                float qp = (__expf((n ? a1[r] : a0[r]) - hh) + 1e-4f) * mm;
                int feat = (2*w + n)*32 + i;
                int fstep = feat >> 4, fq = (i >> 3) & 1, fj = i & 7;
                _Float16 h = (_Float16)qp;
                R2[FR(fstep, fq*32 + tok) + fj] = h;
                R2[FR(16 + fstep, fq*32 + tok) + fj] = (_Float16)(qp - (float)h);
            }
        }
        __syncthreads();

        f32x16 oa, na;
        #pragma unroll
        for (int r = 0; r < 16; ++r) { oa[r] = 0.f; na[r] = 0.f; }
        #pragma unroll
        for (int fs = 0; fs < 16; ++fs) {
            f16x8 ah = *(const f16x8*)&R2[FR(fs, lane)];
            f16x8 al = *(const f16x8*)&R2[FR(16 + fs, lane)];
            oa = mfma16(ah, bfh[fs], oa);
            oa = mfma16(ah, bfl[fs], oa);
            oa = mfma16(al, bfh[fs], oa);
        }
        #pragma unroll
        for (int u = 0; u < 4; ++u) {
            f16x8 ah = *(const f16x8*)&R2[FR(4*w + u, lane)];
            f16x8 al = *(const f16x8*)&R2[FR(16 + 4*w + u, lane)];
            na = mfma16(ah, bnh[u], na);
            na = mfma16(ah, bnl[u], na);
            na = mfma16(al, bnh[u], na);
        }
        if (i == 0)
            #pragma unroll
            for (int r = 0; r < 16; ++r) atomicAdd(&norms[rowf(r, q)], na[r]);
        __syncthreads();

        float* ob = out + ((size_t)b*NN + t0) * DVV + w*32 + i;
        #pragma unroll
        for (int r = 0; r < 16; ++r) {
            int tok = rowf(r, q);
            ob[(size_t)tok * DVV] = oa[r] / norms[tok];
        }
    }
}

extern "C" void kernel_launch(void* const* d_in, const int* in_sizes, int n_in,
                              void* d_out, int out_size, void* d_ws, size_t ws_size,
                              hipStream_t stream) {
    const float* Q     = (const float*)d_in[0];
    const float* K     = (const float*)d_in[1];
    const float* V     = (const float*)d_in[2];
    const float* mask  = (const float*)d_in[3];
    const float* omega = (const float*)d_in[4];
    float* out = (float*)d_out;

    char* ws = (char*)d_ws;
    _Float16* omh    = (_Float16*)(ws);                       // 64 KB
    _Float16* oml    = (_Float16*)(ws + (64 << 10));          // 64 KB
    unsigned* kmaxord = (unsigned*)(ws + (128 << 10));        // 32 B
    float*    ksum   = (float*)(ws + (132 << 10));            // 8 KB
    float*    pks    = (float*)(ws + (140 << 10));            // 256 KB
    _Float16* kvph   = (_Float16*)(ws + (400 << 10));         // 512 KB
    _Float16* kvpl   = (_Float16*)(ws + (912 << 10));         // 512 KB
    float*    pkv    = (float*)(ws + (2 << 20));              // 32 MB

    pack_kernel<<<16, 256, 0, stream>>>(omega, omh, oml, kmaxord);
    kmax_kernel<<<dim3(32, BB), 256, 0, stream>>>(K, omh, kmaxord);
    kv_kernel<<<dim3(PP, BB), 256, 0, stream>>>(K, V, mask, omh, oml, kmaxord, pkv, pks);
    reduce_kernel<<<dim3(128, BB), 256, 0, stream>>>(pkv, pks, ksum, kvph, kvpl);
    out_kernel<<<dim3(32, BB), 256, 0, stream>>>(Q, mask, omh, oml, ksum, kvph, kvpl, out);
}